// Round 10
// baseline (119.774 us; speedup 1.0000x reference)
//
#include <hip/hip_runtime.h>
#include <stdint.h>

// Fused 3-layer MLP via MFMA with split-bf16 (hi+lo) 3-term products:
//   out = relu(relu(x@W0+b0)@W1+b1)@W2+b2
// x: [N,128] f32, W0:[128,32], W1:[32,32], W2:[32,16], out:[N,16] f32.
// edge_index/edge_weight unused (ChebConv K=1).
//
// R10 = R9 + deep DMA pipeline (T3/T4 style):
//  - TRIPLE-buffered wave-private x staging (3 x 8KB/wave, depth-2
//    prefetch: STAGE(k+2) issued while computing k)
//  - COUNTED vmcnt at loop top (vmcnt(12), never 0): retires only the
//    needed 8-op DMA batch; previous iteration's 4 stores + next
//    prefetch stay in flight. R9's vmcnt(0) stalled ~300cyc/tile on
//    store drain (stores issued ~0cyc before the wait).
//    Issue-order audit: prologue STAGE(0),STAGE(1),vmcnt(8);
//    loop top k: outstanding = STAGE(k)8,stores(k-2)4,STAGE(k+1)8,
//    stores(k-1)4 -> vmcnt(12) retires STAGE(k)+stores(k-2). k=0/1 safe.
//  - LDS: 96 xbuf + 22 wlds + 10.25 hbuf = 128.25 KB, 1 block/CU.
//
// MFMA frag layouts (m89-verified):
//  A: lane l holds A[l&15][8*(l>>4)+j], j=0..7
//  B: lane l holds B[8*(l>>4)+j][l&15]
//  C/D: lane l holds D[4*(l>>4)+i][l&15], i=0..3
// Split: v = hi + lo, hi = trunc-to-bf16 (bit mask, exact),
// lo = rne-bf16(v - hi); product = ah*bh + al*bh + ah*bl (~f32 accuracy).
// Staging swizzle (rule 21): LDS dest linear; per-lane global source
// granule (t ^ row); fragment read applies same XOR.

#define N_IN  128
#define HID   32
#define N_OUT 16

using f32x4  = __attribute__((ext_vector_type(4))) float;
using short8 = __attribute__((ext_vector_type(8))) short;
using uint4v = __attribute__((ext_vector_type(4))) unsigned int;

#define N_CHUNKS 22
#define TOTAL_WF_SHORTS (N_CHUNKS * 512)
#define WLDS_GRANULES (N_CHUNKS * 64)   // 16B granules

__device__ __forceinline__ unsigned fu(float f) {
    union { float f; unsigned u; } v; v.f = f; return v.u;
}
__device__ __forceinline__ float uf(unsigned u) {
    union { unsigned u; float f; } v; v.u = u; return v.f;
}
__device__ __forceinline__ unsigned short f2bf_rne(float f) {
    unsigned u = fu(f);
    return (unsigned short)((u + 0x7fffu + ((u >> 16) & 1u)) >> 16);
}

__global__ void split_weights(const float* __restrict__ W0,
                              const float* __restrict__ W1,
                              const float* __restrict__ W2,
                              unsigned short* __restrict__ wf) {
    int idx = blockIdx.x * blockDim.x + threadIdx.x;
    if (idx >= TOTAL_WF_SHORTS) return;
    int chunk  = idx >> 9;
    int within = idx & 511;
    int lane = within >> 3;
    int j    = within & 7;
    const float* W; int ncol, k, col, hl;
    if (chunk < 16) {
        int kc = chunk >> 2, nh = (chunk >> 1) & 1; hl = chunk & 1;
        k = kc * 32 + 8 * (lane >> 4) + j; col = nh * 16 + (lane & 15);
        W = W0; ncol = HID;
    } else if (chunk < 20) {
        int c2 = chunk - 16, nh = c2 >> 1; hl = c2 & 1;
        k = 8 * (lane >> 4) + j; col = nh * 16 + (lane & 15);
        W = W1; ncol = HID;
    } else {
        hl = chunk - 20;
        k = 8 * (lane >> 4) + j; col = lane & 15;
        W = W2; ncol = N_OUT;
    }
    float v = W[k * ncol + col];
    unsigned hi_bits = fu(v) & 0xFFFF0000u;
    wf[idx] = (hl == 0) ? (unsigned short)(hi_bits >> 16)
                        : f2bf_rne(v - uf(hi_bits));
}

#define MFMA3(acc, ah, al, bh, bl)                                          \
    do {                                                                    \
        acc = __builtin_amdgcn_mfma_f32_16x16x32_bf16(ah, bh, acc, 0, 0, 0);\
        acc = __builtin_amdgcn_mfma_f32_16x16x32_bf16(al, bh, acc, 0, 0, 0);\
        acc = __builtin_amdgcn_mfma_f32_16x16x32_bf16(ah, bl, acc, 0, 0, 0);\
    } while (0)

#define GAS1(p) ((const unsigned int __attribute__((address_space(1)))*)(uintptr_t)(p))
#define LAS3(p) ((unsigned int __attribute__((address_space(3)))*)(uintptr_t)(p))

__global__ __launch_bounds__(256, 1) void gnn_mfma(
    const float* __restrict__ x, const unsigned short* __restrict__ wf,
    const float* __restrict__ b0, const float* __restrict__ b1,
    const float* __restrict__ b2, float* __restrict__ out,
    int n_tiles, int stride)
{
    __shared__ __align__(16) unsigned short wlds[N_CHUNKS * 512];  // 22 KB
    // wave-private transpose buffer: [wave][hl][row 16][col 32 + pad 8]
    __shared__ __align__(16) unsigned short hbuf[4][2][16][40];    // 10.25 KB
    // wave-private x staging TRIPLE-buffer: [wave][buf 3][16 rows x 128 f32]
    __shared__ __align__(16) float xbuf[4][3][2048];               // 96 KB

    const int tid  = threadIdx.x;
    const int wave = tid >> 6;
    const int l    = tid & 63;
    const int r16  = l & 15;
    const int g    = l >> 4;

    // ---- stage weight fragments into LDS once per block ----
    {
        const uint4v* wfv = reinterpret_cast<const uint4v*>(wf);
        uint4v* wl = reinterpret_cast<uint4v*>(wlds);
        for (int gg = tid; gg < WLDS_GRANULES; gg += 256)
            wl[gg] = wfv[gg];
    }
    __syncthreads();   // the only block-wide barrier

    const short8* WL = reinterpret_cast<const short8*>(wlds);

    const float bc0a = b0[r16], bc0b = b0[16 + r16];
    const float bc1a = b1[r16], bc1b = b1[16 + r16];
    const float bc2  = b2[r16];

    const int gw = blockIdx.x * 4 + wave;   // global wave id

    // staging geometry: instruction i writes LDS granules [i*64 + lane]
    // (linear, HW: base + lane*16B). LDS granule (row, t) holds global
    // granule (row, t ^ row) -> per-lane source is the inverse-swizzled addr.
    const int srow = l >> 5;   // 0/1: row parity within instruction
    const int st   = l & 31;   // granule within row

    #define STAGE(buf, tileidx)                                                \
    do {                                                                       \
        const float* sb_ = x + (size_t)(tileidx) * 16 * N_IN;                  \
        _Pragma("unroll")                                                      \
        for (int i_ = 0; i_ < 8; ++i_) {                                       \
            int row_ = i_ * 2 + srow;                                          \
            const float* src_ = sb_ + row_ * N_IN + ((st ^ row_) << 2);        \
            float* dst_ = &xbuf[wave][buf][i_ * 256];                          \
            __builtin_amdgcn_global_load_lds(GAS1(src_), LAS3(dst_), 16, 0, 0);\
        }                                                                      \
    } while (0)

    // ---- prologue: depth-2 prefetch ----
    {
        int t1 = gw + stride;
        STAGE(0, gw);
        STAGE(1, (t1 < n_tiles) ? t1 : gw);
    }
    asm volatile("s_waitcnt vmcnt(8)" ::: "memory");   // STAGE(0) complete

    int b = 0;
    for (int tile = gw; tile < n_tiles; tile += stride) {
        const int nb = tile * 16;

        // counted wait: current buffer's 8-op DMA batch retired; stores +
        // next prefetch stay in flight (audit in header comment)
        asm volatile("s_waitcnt vmcnt(12)" ::: "memory");
        __builtin_amdgcn_sched_barrier(0);

        // swizzled fragment reads
        f32x4 xa[4], xbv[4];
        {
            const f32x4* rb = reinterpret_cast<const f32x4*>(&xbuf[wave][b][r16 * 128]);
            #pragma unroll
            for (int kc = 0; kc < 4; ++kc) {
                int t0 = g * 2 + kc * 8;
                xa[kc]  = rb[t0 ^ r16];
                xbv[kc] = rb[(t0 + 1) ^ r16];
            }
        }

        // depth-2 prefetch: stage tile k+2 into buffer (b+2)%3
        {
            int ntt = tile + 2 * stride;
            int pf = (ntt < n_tiles) ? ntt : tile;   // tail: restage self, never read
            int b2i = (b + 2 >= 3) ? (b - 1) : (b + 2);
            STAGE(b2i, pf);
        }

        // -------- layer 0: h0 = relu(x @ W0 + b0), K=128 --------
        f32x4 acc0 = {0.f, 0.f, 0.f, 0.f};
        f32x4 acc1 = {0.f, 0.f, 0.f, 0.f};

        #pragma unroll
        for (int kc = 0; kc < 4; ++kc) {
            float f[8] = {xa[kc][0], xa[kc][1], xa[kc][2], xa[kc][3],
                          xbv[kc][0], xbv[kc][1], xbv[kc][2], xbv[kc][3]};
            uint4v hv, lv;
            #pragma unroll
            for (int p = 0; p < 4; ++p) {
                unsigned u0 = fu(f[2 * p]), u1 = fu(f[2 * p + 1]);
                unsigned h0b = u0 & 0xFFFF0000u, h1b = u1 & 0xFFFF0000u;
                hv[p] = h1b | (u0 >> 16);
                float l0 = f[2 * p] - uf(h0b), l1 = f[2 * p + 1] - uf(h1b);
                lv[p] = (fu(l1) & 0xFFFF0000u) | (fu(l0) >> 16);
            }
            short8 ah = __builtin_bit_cast(short8, hv);
            short8 al = __builtin_bit_cast(short8, lv);
            short8 w0h0 = WL[(kc * 4 + 0) * 64 + l];
            short8 w0l0 = WL[(kc * 4 + 1) * 64 + l];
            short8 w0h1 = WL[(kc * 4 + 2) * 64 + l];
            short8 w0l1 = WL[(kc * 4 + 3) * 64 + l];
            MFMA3(acc0, ah, al, w0h0, w0l0);
            MFMA3(acc1, ah, al, w0h1, w0l1);
        }

        // bias + relu, split hi/lo, wave-private LDS transpose (no barrier)
        #pragma unroll
        for (int i = 0; i < 4; ++i) {
            int row = 4 * g + i;
            float h = fmaxf(acc0[i] + bc0a, 0.f);
            unsigned hb = fu(h) & 0xFFFF0000u;
            hbuf[wave][0][row][r16] = (unsigned short)(hb >> 16);
            hbuf[wave][1][row][r16] = (unsigned short)(fu(h - uf(hb)) >> 16);
            float h2 = fmaxf(acc1[i] + bc0b, 0.f);
            unsigned hb2 = fu(h2) & 0xFFFF0000u;
            hbuf[wave][0][row][16 + r16] = (unsigned short)(hb2 >> 16);
            hbuf[wave][1][row][16 + r16] = (unsigned short)(fu(h2 - uf(hb2)) >> 16);
        }
        short8 h0h = *reinterpret_cast<const short8*>(&hbuf[wave][0][r16][g * 8]);
        short8 h0l = *reinterpret_cast<const short8*>(&hbuf[wave][1][r16][g * 8]);

        // -------- layer 1: h1 = relu(h0 @ W1 + b1), K=32 --------
        f32x4 acc2 = {0.f, 0.f, 0.f, 0.f};
        f32x4 acc3 = {0.f, 0.f, 0.f, 0.f};
        {
            short8 w1h0 = WL[(16 + 0) * 64 + l];
            short8 w1l0 = WL[(16 + 1) * 64 + l];
            short8 w1h1 = WL[(16 + 2) * 64 + l];
            short8 w1l1 = WL[(16 + 3) * 64 + l];
            MFMA3(acc2, h0h, h0l, w1h0, w1l0);
            MFMA3(acc3, h0h, h0l, w1h1, w1l1);
        }
        #pragma unroll
        for (int i = 0; i < 4; ++i) {
            int row = 4 * g + i;
            float h = fmaxf(acc2[i] + bc1a, 0.f);
            unsigned hb = fu(h) & 0xFFFF0000u;
            hbuf[wave][0][row][r16] = (unsigned short)(hb >> 16);
            hbuf[wave][1][row][r16] = (unsigned short)(fu(h - uf(hb)) >> 16);
            float h2 = fmaxf(acc3[i] + bc1b, 0.f);
            unsigned hb2 = fu(h2) & 0xFFFF0000u;
            hbuf[wave][0][row][16 + r16] = (unsigned short)(hb2 >> 16);
            hbuf[wave][1][row][16 + r16] = (unsigned short)(fu(h2 - uf(hb2)) >> 16);
        }
        short8 h1h = *reinterpret_cast<const short8*>(&hbuf[wave][0][r16][g * 8]);
        short8 h1l = *reinterpret_cast<const short8*>(&hbuf[wave][1][r16][g * 8]);

        // -------- layer 2: o = h1 @ W2 + b2, K=32, N=16 --------
        f32x4 accO = {0.f, 0.f, 0.f, 0.f};
        {
            short8 w2h = WL[(20) * 64 + l];
            short8 w2l = WL[(21) * 64 + l];
            MFMA3(accO, h1h, h1l, w2h, w2l);
        }
        #pragma unroll
        for (int i = 0; i < 4; ++i) {
            int row = 4 * g + i;
            __builtin_nontemporal_store(
                accO[i] + bc2, out + (size_t)(nb + row) * N_OUT + r16);
        }

        b = (b == 2) ? 0 : (b + 1);
    }
    #undef STAGE
}

extern "C" void kernel_launch(void* const* d_in, const int* in_sizes, int n_in,
                              void* d_out, int out_size, void* d_ws, size_t ws_size,
                              hipStream_t stream) {
    // setup_inputs() order: x, edge_index, edge_weight, W0, b0, W1, b1, W2, b2
    const float* x  = (const float*)d_in[0];
    const float* W0 = (const float*)d_in[3];
    const float* b0 = (const float*)d_in[4];
    const float* W1 = (const float*)d_in[5];
    const float* b1 = (const float*)d_in[6];
    const float* W2 = (const float*)d_in[7];
    const float* b2 = (const float*)d_in[8];
    float* out = (float*)d_out;
    unsigned short* wf = (unsigned short*)d_ws;   // 22 KB of fragment data

    int n_nodes = in_sizes[0] / N_IN;             // 1,000,000
    int n_tiles = n_nodes / 16;                   // 62,500 (exact)

    split_weights<<<(TOTAL_WF_SHORTS + 255) / 256, 256, 0, stream>>>(W0, W1, W2, wf);

    const int n_blocks = 256;                     // 1 block/CU (128.25KB LDS)
    const int n_waves_total = n_blocks * 4;       // 1024 waves
    gnn_mfma<<<dim3(n_blocks), dim3(256), 0, stream>>>(
        x, wf, b0, b1, b2, out, n_tiles, n_waves_total);
}

// Round 11
// 116.974 us; speedup vs baseline: 1.0239x; 1.0239x over previous
//
#include <hip/hip_runtime.h>
#include <stdint.h>

// Fused 3-layer MLP via MFMA with split-bf16 (hi+lo) 3-term products:
//   out = relu(relu(x@W0+b0)@W1+b1)@W2+b2
// x: [N,128] f32, W0:[128,32], W1:[32,32], W2:[32,16], out:[N,16] f32.
// edge_index/edge_weight unused (ChebConv K=1).
//
// R11 = R9 (best, 113.6us: DMA-staged x, wave-private LDS double buffer,
// both-sides swizzle, 1 block/CU persistent) + ONE change:
//   counted loop-top wait vmcnt(4) instead of vmcnt(0).
// R9's vmcnt(0) also drained the previous iteration's 4 nontemporal
// stores (issued ~50cyc before the wait -> ~300cyc stall/tile). Audit:
//   prologue: STAGE(0); vmcnt(0)                 -> buf0 landed
//   iter k top: outstanding = STAGE(k+1)[8] + stores(k)[4]
//   vmcnt(4) retires the 8 DMA ops (issue order: STAGE before stores),
//   leaves stores in flight. Steady state consistent for all k.
// (R10's triple-buffer+vmcnt(12) bundle regressed; deep prefetch at
// 4 waves/CU thrashes, so depth stays at 1.)
//
// MFMA frag layouts (m89-verified):
//  A: lane l holds A[l&15][8*(l>>4)+j], j=0..7
//  B: lane l holds B[8*(l>>4)+j][l&15]
//  C/D: lane l holds D[4*(l>>4)+i][l&15], i=0..3
// Split: v = hi + lo, hi = trunc-to-bf16 (bit mask, exact),
// lo = rne-bf16(v - hi); product = ah*bh + al*bh + ah*bl (~f32 accuracy).
// Staging swizzle (rule 21): LDS dest linear; per-lane global source
// granule (t ^ row); fragment read applies the same XOR.

#define N_IN  128
#define HID   32
#define N_OUT 16

using f32x4  = __attribute__((ext_vector_type(4))) float;
using short8 = __attribute__((ext_vector_type(8))) short;
using uint4v = __attribute__((ext_vector_type(4))) unsigned int;

#define N_CHUNKS 22
#define TOTAL_WF_SHORTS (N_CHUNKS * 512)
#define WLDS_GRANULES (N_CHUNKS * 64)   // 16B granules

__device__ __forceinline__ unsigned fu(float f) {
    union { float f; unsigned u; } v; v.f = f; return v.u;
}
__device__ __forceinline__ float uf(unsigned u) {
    union { unsigned u; float f; } v; v.u = u; return v.f;
}
__device__ __forceinline__ unsigned short f2bf_rne(float f) {
    unsigned u = fu(f);
    return (unsigned short)((u + 0x7fffu + ((u >> 16) & 1u)) >> 16);
}

__global__ void split_weights(const float* __restrict__ W0,
                              const float* __restrict__ W1,
                              const float* __restrict__ W2,
                              unsigned short* __restrict__ wf) {
    int idx = blockIdx.x * blockDim.x + threadIdx.x;
    if (idx >= TOTAL_WF_SHORTS) return;
    int chunk  = idx >> 9;
    int within = idx & 511;
    int lane = within >> 3;
    int j    = within & 7;
    const float* W; int ncol, k, col, hl;
    if (chunk < 16) {
        int kc = chunk >> 2, nh = (chunk >> 1) & 1; hl = chunk & 1;
        k = kc * 32 + 8 * (lane >> 4) + j; col = nh * 16 + (lane & 15);
        W = W0; ncol = HID;
    } else if (chunk < 20) {
        int c2 = chunk - 16, nh = c2 >> 1; hl = c2 & 1;
        k = 8 * (lane >> 4) + j; col = nh * 16 + (lane & 15);
        W = W1; ncol = HID;
    } else {
        hl = chunk - 20;
        k = 8 * (lane >> 4) + j; col = lane & 15;
        W = W2; ncol = N_OUT;
    }
    float v = W[k * ncol + col];
    unsigned hi_bits = fu(v) & 0xFFFF0000u;
    wf[idx] = (hl == 0) ? (unsigned short)(hi_bits >> 16)
                        : f2bf_rne(v - uf(hi_bits));
}

#define MFMA3(acc, ah, al, bh, bl)                                          \
    do {                                                                    \
        acc = __builtin_amdgcn_mfma_f32_16x16x32_bf16(ah, bh, acc, 0, 0, 0);\
        acc = __builtin_amdgcn_mfma_f32_16x16x32_bf16(al, bh, acc, 0, 0, 0);\
        acc = __builtin_amdgcn_mfma_f32_16x16x32_bf16(ah, bl, acc, 0, 0, 0);\
    } while (0)

#define GAS1(p) ((const unsigned int __attribute__((address_space(1)))*)(uintptr_t)(p))
#define LAS3(p) ((unsigned int __attribute__((address_space(3)))*)(uintptr_t)(p))

__global__ __launch_bounds__(256, 1) void gnn_mfma(
    const float* __restrict__ x, const unsigned short* __restrict__ wf,
    const float* __restrict__ b0, const float* __restrict__ b1,
    const float* __restrict__ b2, float* __restrict__ out,
    int n_tiles, int stride)
{
    __shared__ __align__(16) unsigned short wlds[N_CHUNKS * 512];  // 22 KB
    // wave-private transpose buffer: [wave][hl][row 16][col 32 + pad 8]
    __shared__ __align__(16) unsigned short hbuf[4][2][16][40];    // 10.25 KB
    // wave-private x staging double-buffer: [wave][buf][16 rows x 128 f32]
    __shared__ __align__(16) float xbuf[4][2][2048];               // 64 KB

    const int tid  = threadIdx.x;
    const int wave = tid >> 6;
    const int l    = tid & 63;
    const int r16  = l & 15;
    const int g    = l >> 4;

    // ---- stage weight fragments into LDS once per block ----
    {
        const uint4v* wfv = reinterpret_cast<const uint4v*>(wf);
        uint4v* wl = reinterpret_cast<uint4v*>(wlds);
        for (int gg = tid; gg < WLDS_GRANULES; gg += 256)
            wl[gg] = wfv[gg];
    }
    __syncthreads();   // the only block-wide barrier

    const short8* WL = reinterpret_cast<const short8*>(wlds);

    const float bc0a = b0[r16], bc0b = b0[16 + r16];
    const float bc1a = b1[r16], bc1b = b1[16 + r16];
    const float bc2  = b2[r16];

    const int gw = blockIdx.x * 4 + wave;   // global wave id

    // staging geometry: instruction i writes LDS granules [i*64 + lane]
    // (linear, HW: base + lane*16B). LDS granule (row, t) holds global
    // granule (row, t ^ row) -> per-lane source is the inverse-swizzled addr.
    const int srow = l >> 5;   // 0/1: row parity within instruction
    const int st   = l & 31;   // granule within row

    #define STAGE(buf, tileidx)                                                \
    do {                                                                       \
        const float* sb_ = x + (size_t)(tileidx) * 16 * N_IN;                  \
        _Pragma("unroll")                                                      \
        for (int i_ = 0; i_ < 8; ++i_) {                                       \
            int row_ = i_ * 2 + srow;                                          \
            const float* src_ = sb_ + row_ * N_IN + ((st ^ row_) << 2);        \
            float* dst_ = &xbuf[wave][buf][i_ * 256];                          \
            __builtin_amdgcn_global_load_lds(GAS1(src_), LAS3(dst_), 16, 0, 0);\
        }                                                                      \
    } while (0)

    int b = 0;
    STAGE(0, gw);   // prologue: first tile -> buf 0 (gw < n_tiles always)
    asm volatile("s_waitcnt vmcnt(0)" ::: "memory");   // buf0 landed

    for (int tile = gw; tile < n_tiles; tile += stride) {
        const int nb = tile * 16;

        // counted wait: retire current buffer's 8 DMA ops; previous
        // iteration's 4 stores stay in flight (audit in header comment)
        asm volatile("s_waitcnt vmcnt(4)" ::: "memory");
        __builtin_amdgcn_sched_barrier(0);

        // swizzled fragment reads
        f32x4 xa[4], xbv[4];
        {
            const f32x4* rb = reinterpret_cast<const f32x4*>(&xbuf[wave][b][r16 * 128]);
            #pragma unroll
            for (int kc = 0; kc < 4; ++kc) {
                int t0 = g * 2 + kc * 8;
                xa[kc]  = rb[t0 ^ r16];
                xbv[kc] = rb[(t0 + 1) ^ r16];
            }
        }

        // prefetch next tile into the other buffer (fire-and-forget)
        {
            int ntt = tile + stride;
            int pf = (ntt < n_tiles) ? ntt : tile;   // tail: restage self, never read
            STAGE(b ^ 1, pf);
        }

        // -------- layer 0: h0 = relu(x @ W0 + b0), K=128 --------
        f32x4 acc0 = {0.f, 0.f, 0.f, 0.f};
        f32x4 acc1 = {0.f, 0.f, 0.f, 0.f};

        #pragma unroll
        for (int kc = 0; kc < 4; ++kc) {
            float f[8] = {xa[kc][0], xa[kc][1], xa[kc][2], xa[kc][3],
                          xbv[kc][0], xbv[kc][1], xbv[kc][2], xbv[kc][3]};
            uint4v hv, lv;
            #pragma unroll
            for (int p = 0; p < 4; ++p) {
                unsigned u0 = fu(f[2 * p]), u1 = fu(f[2 * p + 1]);
                unsigned h0b = u0 & 0xFFFF0000u, h1b = u1 & 0xFFFF0000u;
                hv[p] = h1b | (u0 >> 16);
                float l0 = f[2 * p] - uf(h0b), l1 = f[2 * p + 1] - uf(h1b);
                lv[p] = (fu(l1) & 0xFFFF0000u) | (fu(l0) >> 16);
            }
            short8 ah = __builtin_bit_cast(short8, hv);
            short8 al = __builtin_bit_cast(short8, lv);
            short8 w0h0 = WL[(kc * 4 + 0) * 64 + l];
            short8 w0l0 = WL[(kc * 4 + 1) * 64 + l];
            short8 w0h1 = WL[(kc * 4 + 2) * 64 + l];
            short8 w0l1 = WL[(kc * 4 + 3) * 64 + l];
            MFMA3(acc0, ah, al, w0h0, w0l0);
            MFMA3(acc1, ah, al, w0h1, w0l1);
        }

        // bias + relu, split hi/lo, wave-private LDS transpose (no barrier)
        #pragma unroll
        for (int i = 0; i < 4; ++i) {
            int row = 4 * g + i;
            float h = fmaxf(acc0[i] + bc0a, 0.f);
            unsigned hb = fu(h) & 0xFFFF0000u;
            hbuf[wave][0][row][r16] = (unsigned short)(hb >> 16);
            hbuf[wave][1][row][r16] = (unsigned short)(fu(h - uf(hb)) >> 16);
            float h2 = fmaxf(acc1[i] + bc0b, 0.f);
            unsigned hb2 = fu(h2) & 0xFFFF0000u;
            hbuf[wave][0][row][16 + r16] = (unsigned short)(hb2 >> 16);
            hbuf[wave][1][row][16 + r16] = (unsigned short)(fu(h2 - uf(hb2)) >> 16);
        }
        short8 h0h = *reinterpret_cast<const short8*>(&hbuf[wave][0][r16][g * 8]);
        short8 h0l = *reinterpret_cast<const short8*>(&hbuf[wave][1][r16][g * 8]);

        // -------- layer 1: h1 = relu(h0 @ W1 + b1), K=32 --------
        f32x4 acc2 = {0.f, 0.f, 0.f, 0.f};
        f32x4 acc3 = {0.f, 0.f, 0.f, 0.f};
        {
            short8 w1h0 = WL[(16 + 0) * 64 + l];
            short8 w1l0 = WL[(16 + 1) * 64 + l];
            short8 w1h1 = WL[(16 + 2) * 64 + l];
            short8 w1l1 = WL[(16 + 3) * 64 + l];
            MFMA3(acc2, h0h, h0l, w1h0, w1l0);
            MFMA3(acc3, h0h, h0l, w1h1, w1l1);
        }
        #pragma unroll
        for (int i = 0; i < 4; ++i) {
            int row = 4 * g + i;
            float h = fmaxf(acc2[i] + bc1a, 0.f);
            unsigned hb = fu(h) & 0xFFFF0000u;
            hbuf[wave][0][row][r16] = (unsigned short)(hb >> 16);
            hbuf[wave][1][row][r16] = (unsigned short)(fu(h - uf(hb)) >> 16);
            float h2 = fmaxf(acc3[i] + bc1b, 0.f);
            unsigned hb2 = fu(h2) & 0xFFFF0000u;
            hbuf[wave][0][row][16 + r16] = (unsigned short)(hb2 >> 16);
            hbuf[wave][1][row][16 + r16] = (unsigned short)(fu(h2 - uf(hb2)) >> 16);
        }
        short8 h1h = *reinterpret_cast<const short8*>(&hbuf[wave][0][r16][g * 8]);
        short8 h1l = *reinterpret_cast<const short8*>(&hbuf[wave][1][r16][g * 8]);

        // -------- layer 2: o = h1 @ W2 + b2, K=32, N=16 --------
        f32x4 accO = {0.f, 0.f, 0.f, 0.f};
        {
            short8 w2h = WL[(20) * 64 + l];
            short8 w2l = WL[(21) * 64 + l];
            MFMA3(accO, h1h, h1l, w2h, w2l);
        }
        #pragma unroll
        for (int i = 0; i < 4; ++i) {
            int row = 4 * g + i;
            __builtin_nontemporal_store(
                accO[i] + bc2, out + (size_t)(nb + row) * N_OUT + r16);
        }

        b ^= 1;
    }
    #undef STAGE
}

extern "C" void kernel_launch(void* const* d_in, const int* in_sizes, int n_in,
                              void* d_out, int out_size, void* d_ws, size_t ws_size,
                              hipStream_t stream) {
    // setup_inputs() order: x, edge_index, edge_weight, W0, b0, W1, b1, W2, b2
    const float* x  = (const float*)d_in[0];
    const float* W0 = (const float*)d_in[3];
    const float* b0 = (const float*)d_in[4];
    const float* W1 = (const float*)d_in[5];
    const float* b1 = (const float*)d_in[6];
    const float* W2 = (const float*)d_in[7];
    const float* b2 = (const float*)d_in[8];
    float* out = (float*)d_out;
    unsigned short* wf = (unsigned short*)d_ws;   // 22 KB of fragment data

    int n_nodes = in_sizes[0] / N_IN;             // 1,000,000
    int n_tiles = n_nodes / 16;                   // 62,500 (exact)

    split_weights<<<(TOTAL_WF_SHORTS + 255) / 256, 256, 0, stream>>>(W0, W1, W2, wf);

    const int n_blocks = 256;                     // 1 block/CU (96.25KB LDS)
    const int n_waves_total = n_blocks * 4;       // 1024 waves
    gnn_mfma<<<dim3(n_blocks), dim3(256), 0, stream>>>(
        x, wf, b0, b1, b2, out, n_tiles, n_waves_total);
}

// Round 14
// 111.141 us; speedup vs baseline: 1.0777x; 1.0525x over previous
//
#include <hip/hip_runtime.h>
#include <stdint.h>

// Fused 3-layer MLP via SWAPPED-operand MFMA with split-bf16 (hi+lo):
//   out = relu(relu(x@W0+b0)@W1+b1)@W2+b2, computed as h^T = W^T @ x^T.
// x: [N,128] f32, W0:[128,32], W1:[32,32], W2:[32,16], out:[N,16] f32.
// edge_index/edge_weight unused (ChebConv K=1).
//
// R14 = R12/R13 resubmitted verbatim (both benches died in infra:
// UnresponsiveContainer before push; no kernel signal). Structure = R9
// (DMA-staged x double-buffer, both-sides swizzle, 1 block/CU persistent,
// vmcnt(0) loop top) + swapped MFMA (A=W^T, B=x^T / h^T):
//  - x B-frag == old A-frag bit-for-bit: staging/swizzle/split unchanged
//  - D holds h^T: lane l = units {4g+i}u{16+4g+i} of node r16. With W1/W2
//    K-dim reordered by rho(8g+j)= (j<4? 4g+j : 16+4g+j-4) (bijective),
//    the next layer's B-frag is a PURE IN-LANE repack: both LDS hbuf
//    transposes (16 ds_write_u16 + 2 ds_read_b128 + RAW waits, x2) GONE.
//  - final store = ONE dwordx4/lane (out[node r16][4g..4g+3]), full 64B
//    lines, instead of 4 scattered nt dwords.
// LDS now 86 KB (wlds 22 + xbuf 64).
//
// MFMA frag layouts (m89-verified):
//  A: lane l holds A[l&15][8*(l>>4)+j], j=0..7
//  B: lane l holds B[8*(l>>4)+j][l&15]
//  C/D: lane l holds D[4*(l>>4)+i][l&15], i=0..3
// Split: v = hi + lo, hi = trunc-to-bf16 (bit mask, exact),
// lo = rne-bf16(v - hi); product = wh*xh + wl*xh + wh*xl (~f32 accuracy).

#define N_IN  128
#define HID   32
#define N_OUT 16

using f32x4  = __attribute__((ext_vector_type(4))) float;
using short8 = __attribute__((ext_vector_type(8))) short;
using uint4v = __attribute__((ext_vector_type(4))) unsigned int;

#define N_CHUNKS 22
#define TOTAL_WF_SHORTS (N_CHUNKS * 512)
#define WLDS_GRANULES (N_CHUNKS * 64)   // 16B granules

__device__ __forceinline__ unsigned fu(float f) {
    union { float f; unsigned u; } v; v.f = f; return v.u;
}
__device__ __forceinline__ float uf(unsigned u) {
    union { unsigned u; float f; } v; v.u = u; return v.f;
}
__device__ __forceinline__ unsigned short f2bf_rne(float f) {
    unsigned u = fu(f);
    return (unsigned short)((u + 0x7fffu + ((u >> 16) & 1u)) >> 16);
}

// chunk layout (each chunk = 64 lanes * 8 bf16 = 512 shorts = 1KB):
//  W0 (A = W0^T, 2 M-blocks, K=128): chunks [0,16) = kc*4 + b*2 + hl
//     lane,j: A_b[r16][32kc+8g+j] = W0[32kc+8g+j][16b+r16]   (== old layout)
//  W1 (A = W1^T, rho-reordered K): chunks [16,20) = 16 + b*2 + hl
//     lane,j: W1[rho(8g+j)][16b+r16]
//  W2 (A = W2^T, rho-reordered K): chunks [20,22) = 20 + hl
//     lane,j: W2[rho(8g+j)][r16]
__global__ void split_weights(const float* __restrict__ W0,
                              const float* __restrict__ W1,
                              const float* __restrict__ W2,
                              unsigned short* __restrict__ wf) {
    int idx = blockIdx.x * blockDim.x + threadIdx.x;
    if (idx >= TOTAL_WF_SHORTS) return;
    int chunk  = idx >> 9;
    int within = idx & 511;
    int lane = within >> 3;
    int j    = within & 7;
    int g4   = 4 * (lane >> 4);
    int r16  = lane & 15;
    int rho  = (j < 4) ? (g4 + j) : (16 + g4 + (j - 4));
    float v; int hl;
    if (chunk < 16) {
        int kc = chunk >> 2, b = (chunk >> 1) & 1; hl = chunk & 1;
        int k = kc * 32 + 2 * g4 + j;            // 32kc + 8g + j
        v = W0[k * HID + 16 * b + r16];
    } else if (chunk < 20) {
        int c2 = chunk - 16, b = c2 >> 1; hl = c2 & 1;
        v = W1[rho * HID + 16 * b + r16];
    } else {
        hl = chunk - 20;
        v = W2[rho * N_OUT + r16];
    }
    unsigned hi_bits = fu(v) & 0xFFFF0000u;
    wf[idx] = (hl == 0) ? (unsigned short)(hi_bits >> 16)
                        : f2bf_rne(v - uf(hi_bits));
}

// 3-term split product: A=W(hi/lo), B=x/h(hi/lo)
#define MFMA3(acc, wh, wl, xh, xl)                                          \
    do {                                                                    \
        acc = __builtin_amdgcn_mfma_f32_16x16x32_bf16(wh, xh, acc, 0, 0, 0);\
        acc = __builtin_amdgcn_mfma_f32_16x16x32_bf16(wl, xh, acc, 0, 0, 0);\
        acc = __builtin_amdgcn_mfma_f32_16x16x32_bf16(wh, xl, acc, 0, 0, 0);\
    } while (0)

// split 8 f32 into packed bf16 hi/lo short8 fragments
#define SPLIT8A(farr, AH, AL)                                               \
    do {                                                                    \
        uint4v hv_, lv_;                                                    \
        _Pragma("unroll")                                                   \
        for (int p_ = 0; p_ < 4; ++p_) {                                    \
            unsigned u0_ = fu((farr)[2 * p_]), u1_ = fu((farr)[2 * p_ + 1]);\
            unsigned h0_ = u0_ & 0xFFFF0000u, h1_ = u1_ & 0xFFFF0000u;      \
            hv_[p_] = h1_ | (u0_ >> 16);                                    \
            float l0_ = (farr)[2 * p_] - uf(h0_);                           \
            float l1_ = (farr)[2 * p_ + 1] - uf(h1_);                       \
            lv_[p_] = (fu(l1_) & 0xFFFF0000u) | (fu(l0_) >> 16);            \
        }                                                                   \
        AH = __builtin_bit_cast(short8, hv_);                               \
        AL = __builtin_bit_cast(short8, lv_);                               \
    } while (0)

#define GAS1(p) ((const unsigned int __attribute__((address_space(1)))*)(uintptr_t)(p))
#define LAS3(p) ((unsigned int __attribute__((address_space(3)))*)(uintptr_t)(p))

__global__ __launch_bounds__(256, 1) void gnn_mfma(
    const float* __restrict__ x, const unsigned short* __restrict__ wf,
    const float* __restrict__ b0, const float* __restrict__ b1,
    const float* __restrict__ b2, float* __restrict__ out,
    int n_tiles, int stride)
{
    __shared__ __align__(16) unsigned short wlds[N_CHUNKS * 512];  // 22 KB
    // wave-private x staging double-buffer: [wave][buf][16 rows x 128 f32]
    __shared__ __align__(16) float xbuf[4][2][2048];               // 64 KB

    const int tid  = threadIdx.x;
    const int wave = tid >> 6;
    const int l    = tid & 63;
    const int r16  = l & 15;
    const int g    = l >> 4;

    // ---- stage weight fragments into LDS once per block ----
    {
        const uint4v* wfv = reinterpret_cast<const uint4v*>(wf);
        uint4v* wl = reinterpret_cast<uint4v*>(wlds);
        for (int gg = tid; gg < WLDS_GRANULES; gg += 256)
            wl[gg] = wfv[gg];
    }
    __syncthreads();   // the only block-wide barrier

    const short8* WL = reinterpret_cast<const short8*>(wlds);

    // per-lane biases for units 4g..4g+3 (block0) and 16+4g.. (block1)
    const f32x4 bb0a = *reinterpret_cast<const f32x4*>(b0 + 4 * g);
    const f32x4 bb0b = *reinterpret_cast<const f32x4*>(b0 + 16 + 4 * g);
    const f32x4 bb1a = *reinterpret_cast<const f32x4*>(b1 + 4 * g);
    const f32x4 bb1b = *reinterpret_cast<const f32x4*>(b1 + 16 + 4 * g);
    const f32x4 bb2  = *reinterpret_cast<const f32x4*>(b2 + 4 * g);

    const int gw = blockIdx.x * 4 + wave;   // global wave id

    // staging geometry: instruction i writes LDS granules [i*64 + lane]
    // (linear, HW: base + lane*16B). LDS granule (row, t) holds global
    // granule (row, t ^ row) -> per-lane source is the inverse-swizzled addr.
    const int srow = l >> 5;   // 0/1: row parity within instruction
    const int st   = l & 31;   // granule within row

    #define STAGE(buf, tileidx)                                                \
    do {                                                                       \
        const float* sb_ = x + (size_t)(tileidx) * 16 * N_IN;                  \
        _Pragma("unroll")                                                      \
        for (int i_ = 0; i_ < 8; ++i_) {                                       \
            int row_ = i_ * 2 + srow;                                          \
            const float* src_ = sb_ + row_ * N_IN + ((st ^ row_) << 2);        \
            float* dst_ = &xbuf[wave][buf][i_ * 256];                          \
            __builtin_amdgcn_global_load_lds(GAS1(src_), LAS3(dst_), 16, 0, 0);\
        }                                                                      \
    } while (0)

    int b = 0;
    STAGE(0, gw);   // prologue: first tile -> buf 0 (gw < n_tiles always)

    for (int tile = gw; tile < n_tiles; tile += stride) {
        const int nb = tile * 16;

        // wait for current buffer's DMA to land (R9 semantics)
        asm volatile("s_waitcnt vmcnt(0)" ::: "memory");
        __builtin_amdgcn_sched_barrier(0);

        // swizzled fragment reads: lane wants global granules (r16, t0), (r16, t0+1)
        f32x4 xa[4], xbv[4];
        {
            const f32x4* rb = reinterpret_cast<const f32x4*>(&xbuf[wave][b][r16 * 128]);
            #pragma unroll
            for (int kc = 0; kc < 4; ++kc) {
                int t0 = g * 2 + kc * 8;
                xa[kc]  = rb[t0 ^ r16];
                xbv[kc] = rb[(t0 + 1) ^ r16];
            }
        }

        // prefetch next tile into the other buffer (fire-and-forget)
        {
            int ntt = tile + stride;
            int pf = (ntt < n_tiles) ? ntt : tile;   // tail: restage self, never read
            STAGE(b ^ 1, pf);
        }

        // -------- layer 0: h0^T = W0^T @ x^T (2 M-blocks), K=128 --------
        f32x4 acc0 = {0.f, 0.f, 0.f, 0.f};
        f32x4 acc1 = {0.f, 0.f, 0.f, 0.f};

        #pragma unroll
        for (int kc = 0; kc < 4; ++kc) {
            float f[8] = {xa[kc][0], xa[kc][1], xa[kc][2], xa[kc][3],
                          xbv[kc][0], xbv[kc][1], xbv[kc][2], xbv[kc][3]};
            short8 xh, xl;
            SPLIT8A(f, xh, xl);
            short8 w0h0 = WL[(kc * 4 + 0) * 64 + l];
            short8 w0l0 = WL[(kc * 4 + 1) * 64 + l];
            short8 w0h1 = WL[(kc * 4 + 2) * 64 + l];
            short8 w0l1 = WL[(kc * 4 + 3) * 64 + l];
            MFMA3(acc0, w0h0, w0l0, xh, xl);
            MFMA3(acc1, w0h1, w0l1, xh, xl);
        }

        // bias + relu + in-lane repack to layer-1 B-frag (rho ordering)
        float hf[8];
        #pragma unroll
        for (int i = 0; i < 4; ++i) {
            hf[i]     = fmaxf(acc0[i] + bb0a[i], 0.f);   // units 4g+i
            hf[4 + i] = fmaxf(acc1[i] + bb0b[i], 0.f);   // units 16+4g+i
        }
        short8 hbh, hbl;
        SPLIT8A(hf, hbh, hbl);

        // -------- layer 1: h1^T = W1^T @ h0^T (2 M-blocks), K=32 --------
        f32x4 acc2 = {0.f, 0.f, 0.f, 0.f};
        f32x4 acc3 = {0.f, 0.f, 0.f, 0.f};
        {
            short8 w1h0 = WL[(16 + 0) * 64 + l];
            short8 w1l0 = WL[(16 + 1) * 64 + l];
            short8 w1h1 = WL[(16 + 2) * 64 + l];
            short8 w1l1 = WL[(16 + 3) * 64 + l];
            MFMA3(acc2, w1h0, w1l0, hbh, hbl);
            MFMA3(acc3, w1h1, w1l1, hbh, hbl);
        }
        float hf2[8];
        #pragma unroll
        for (int i = 0; i < 4; ++i) {
            hf2[i]     = fmaxf(acc2[i] + bb1a[i], 0.f);
            hf2[4 + i] = fmaxf(acc3[i] + bb1b[i], 0.f);
        }
        short8 h2h, h2l;
        SPLIT8A(hf2, h2h, h2l);

        // -------- layer 2: out^T = W2^T @ h1^T (1 M-block), K=32 --------
        f32x4 accO = {0.f, 0.f, 0.f, 0.f};
        {
            short8 w2h = WL[(20) * 64 + l];
            short8 w2l = WL[(21) * 64 + l];
            MFMA3(accO, w2h, w2l, h2h, h2l);
        }

        // store: lane holds out[node r16][dims 4g..4g+3] -> one dwordx4
        f32x4 ov;
        #pragma unroll
        for (int i = 0; i < 4; ++i) ov[i] = accO[i] + bb2[i];
        __builtin_nontemporal_store(
            ov, reinterpret_cast<f32x4*>(out + (size_t)(nb + r16) * N_OUT + 4 * g));

        b ^= 1;
    }
    #undef STAGE
}

extern "C" void kernel_launch(void* const* d_in, const int* in_sizes, int n_in,
                              void* d_out, int out_size, void* d_ws, size_t ws_size,
                              hipStream_t stream) {
    // setup_inputs() order: x, edge_index, edge_weight, W0, b0, W1, b1, W2, b2
    const float* x  = (const float*)d_in[0];
    const float* W0 = (const float*)d_in[3];
    const float* b0 = (const float*)d_in[4];
    const float* W1 = (const float*)d_in[5];
    const float* b1 = (const float*)d_in[6];
    const float* W2 = (const float*)d_in[7];
    const float* b2 = (const float*)d_in[8];
    float* out = (float*)d_out;
    unsigned short* wf = (unsigned short*)d_ws;   // 22 KB of fragment data

    int n_nodes = in_sizes[0] / N_IN;             // 1,000,000
    int n_tiles = n_nodes / 16;                   // 62,500 (exact)

    split_weights<<<(TOTAL_WF_SHORTS + 255) / 256, 256, 0, stream>>>(W0, W1, W2, wf);

    const int n_blocks = 256;                     // 1 block/CU (86KB LDS)
    const int n_waves_total = n_blocks * 4;       // 1024 waves
    gnn_mfma<<<dim3(n_blocks), dim3(256), 0, stream>>>(
        x, wf, b0, b1, b2, out, n_tiles, n_waves_total);
}